// Round 7
// baseline (192.231 us; speedup 1.0000x reference)
//
#include <hip/hip_runtime.h>
#include <hip/hip_bf16.h>

#define NB 4
#define CH 128
#define NN 4096
#define KS 8                     // split of the K(v) dim in k_hyp

typedef short bf16x8 __attribute__((ext_vector_type(8)));
typedef float f32x4 __attribute__((ext_vector_type(4)));
typedef float f32x16 __attribute__((ext_vector_type(16)));
using u16 = unsigned short;
using u32 = unsigned int;

__device__ __forceinline__ u16 f2bf(float v) {
  return __builtin_bit_cast(u16, __float2bfloat16(v));
}
__device__ __forceinline__ float bf2f(u16 u) {
  return __builtin_bit_cast(float, ((u32)u) << 16);
}
__device__ __forceinline__ u32 pk2(float a, float b) {
  return (u32)f2bf(a) | ((u32)f2bf(b) << 16);
}

__device__ __forceinline__ void gld16(const void* g, void* l) {
  __builtin_amdgcn_global_load_lds((const __attribute__((address_space(1))) void*)g,
                                   (__attribute__((address_space(3))) void*)l,
                                   16, 0, 0);
}

// ---------------- k_prep: x[b][c][n] -> XA/XG fragment-order aug arrays ------
__global__ __launch_bounds__(256) void k_prep(const float* __restrict__ x,
                                              u16* __restrict__ XA,
                                              u16* __restrict__ XG) {
  __shared__ float ls[128][65];
  __shared__ float sqs[64];
  int blk = blockIdx.x;            // NB*64
  int b = blk >> 6;
  int n0 = (blk & 63) * 64;
  int t = threadIdx.x;
  const float* xb = x + (size_t)b * CH * NN;
  {
    int j = t & 63, cb = t >> 6;
#pragma unroll
    for (int i = 0; i < 32; ++i) {
      int c = cb * 32 + i;
      ls[c][j] = xb[(size_t)c * NN + n0 + j];
    }
  }
  __syncthreads();
  if (t < 64) {
    float s = 0.f;
#pragma unroll
    for (int c = 0; c < 128; ++c) { float v = ls[c][t]; s += v * v; }
    sqs[t] = s;
  }
  __syncthreads();
  int v = t & 31, g = t >> 5;      // g = 0..7
  const u32 one2 = 0x3F803F80u;
#pragma unroll
  for (int vt2 = 0; vt2 < 2; ++vt2) {
    int j = vt2 * 32 + v;
    float sv = sqs[j];
    u16 shi = f2bf(sv);
    u16 slo = f2bf(sv - bf2f(shi));
    size_t tb = ((size_t)b * 128 + (n0 >> 5) + vt2) * 4608;
    for (int s = g; s < 18; s += 8) {
      int k9 = s >> 1, h = s & 1;
      int c0 = k9 * 16 + h * 8;
      u32 wa[4], wg[4];
      if (k9 < 8) {
#pragma unroll
        for (int p = 0; p < 4; ++p) {
          float va = ls[c0 + 2 * p][j], vb = ls[c0 + 2 * p + 1][j];
          wa[p] = pk2(va, vb);
          wg[p] = pk2(-2.f * va, -2.f * vb);
        }
      } else if (h == 0) {
        wa[0] = (u32)shi | ((u32)slo << 16); wa[1] = one2; wa[2] = 0u; wa[3] = 0u;
        wg[0] = one2; wg[1] = (u32)shi | ((u32)slo << 16); wg[2] = 0u; wg[3] = 0u;
      } else {
        wa[0] = wa[1] = wa[2] = wa[3] = 0u;
        wg[0] = wg[1] = wg[2] = wg[3] = 0u;
      }
      *(uint4*)(XA + tb + (size_t)s * 256 + v * 8) = make_uint4(wa[0], wa[1], wa[2], wa[3]);
      *(uint4*)(XG + tb + (size_t)s * 256 + v * 8) = make_uint4(wg[0], wg[1], wg[2], wg[3]);
    }
  }
}

// ---------------- k_xe: MFMA GEMM  xe = xf*W^T + b -> XE2 fragment layout ----
__global__ __launch_bounds__(256) void k_xe(const u16* __restrict__ XA,
                                            const float* __restrict__ W,
                                            const float* __restrict__ bfc,
                                            u16* __restrict__ XE2) {
  __shared__ __align__(16) char sw[32768];   // W bf16 [d][c], XOR-swizzled rows
  int t = threadIdx.x;
  int lane = t & 63, w = t >> 6;
  int r = lane & 31, hi = lane >> 5;
  int b = blockIdx.x >> 5, nt = blockIdx.x & 31;
  int vt = nt * 4 + w;
  {
    int d = t >> 1, half = t & 1;
    const float4* src = (const float4*)(W + (size_t)d * 128 + half * 64);
    int rowoff = d * 256, sz = (d & 7) << 4;
#pragma unroll
    for (int ch = 0; ch < 8; ++ch) {
      float4 f0 = src[ch * 2], f1 = src[ch * 2 + 1];
      *(uint4*)(sw + ((rowoff + half * 128 + ch * 16) ^ sz)) =
          make_uint4(pk2(f0.x, f0.y), pk2(f0.z, f0.w), pk2(f1.x, f1.y), pk2(f1.z, f1.w));
    }
  }
  float bias[4];
#pragma unroll
  for (int dt = 0; dt < 4; ++dt) bias[dt] = bfc[dt * 32 + r];
  __syncthreads();
  const u16* abase = XA + ((size_t)(b * 128 + vt)) * 4608;
  bf16x8 a[8];
#pragma unroll
  for (int k9 = 0; k9 < 8; ++k9)
    a[k9] = *(const bf16x8*)(abase + (k9 * 2 + hi) * 256 + r * 8);
  f32x16 acc[4];
#pragma unroll
  for (int dt = 0; dt < 4; ++dt)
#pragma unroll
    for (int q = 0; q < 16; ++q) acc[dt][q] = bias[dt];
#pragma unroll
  for (int k9 = 0; k9 < 8; ++k9) {
#pragma unroll
    for (int dt = 0; dt < 4; ++dt) {
      int d = dt * 32 + r;
      bf16x8 bf_ = *(const bf16x8*)(sw + ((d * 256 + k9 * 32 + hi * 16) ^ ((d & 7) << 4)));
      acc[dt] = __builtin_amdgcn_mfma_f32_32x32x16_bf16(a[k9], bf_, acc[dt], 0, 0, 0);
    }
  }
  u16* base = XE2 + ((size_t)(b * 128 + vt)) * 4096;
#pragma unroll
  for (int dt = 0; dt < 4; ++dt)
#pragma unroll
    for (int h = 0; h < 2; ++h)
#pragma unroll
      for (int hi2 = 0; hi2 < 2; ++hi2) {
        int q0 = h * 8 + hi2 * 4;
        u32 w0 = pk2(acc[dt][q0], acc[dt][q0 + 1]);
        u32 w1 = pk2(acc[dt][q0 + 2], acc[dt][q0 + 3]);
        *(uint2*)(base + (((dt * 2 + h) * 2 + hi2) * 32 + r) * 8 + hi * 4) =
            make_uint2(w0, w1);
      }
}

// ---------------- fused: P=(d2<256); out += P*B2 ; deg += rowsum(P) ----------
// MODE 0 (pass A): fragment-layout partials + deg atomics.
// MODE 1 (pass B): [row][d] layout partials, no deg.
// grid: 1024 = b(4) x et(32) x ks(8); 4 waves, wave = 32 out-rows x 128 d.
// launch_bounds(256,3): 3 waves/EU -> total reg cap 170 (84 VGPR + 64 AGPR
// = 148 fits, no spill); LDS 34.8KB allows 4 blocks/CU, VGPR gives 3.
template <int MODE>
__global__ __launch_bounds__(256, 3) void k_hyp(const u16* __restrict__ XAg,
                                                const u16* __restrict__ XGg,
                                                const u16* __restrict__ B2g,
                                                u16* __restrict__ outP,
                                                float* __restrict__ deg) {
  __shared__ __align__(16) char smem[34816];
  int t = threadIdx.x;
  int lane = t & 63, w = t >> 6;
  int r = lane & 31, hi = lane >> 5;
  int bid = blockIdx.x;
  int b = bid >> 8;
  int et = (bid >> 3) & 31;
  int ks = bid & 7;
  int e0 = et * 128;
  int vt0 = ks * 16;               // 16 v-tiles of 32 per split

  bf16x8 B1[9];
  {
    const u16* g = XGg + ((size_t)(b * 128 + et * 4 + w)) * 4608 + (hi * 32 + r) * 8;
#pragma unroll
    for (int k9 = 0; k9 < 9; ++k9) B1[k9] = *(const bf16x8*)(g + k9 * 512);
  }

  f32x16 acc2[4];
#pragma unroll
  for (int dt = 0; dt < 4; ++dt)
#pragma unroll
    for (int q = 0; q < 16; ++q) acc2[dt][q] = 0.f;
  float dg = 0.f;
  f32x16 zero;
#pragma unroll
  for (int q = 0; q < 16; ++q) zero[q] = 0.f;

  const u16* xa_t = XAg + ((size_t)(b * 128 + vt0)) * 4608;
  const u16* b2_t = B2g + ((size_t)(b * 128 + vt0)) * 4096;

  // prologue: stage tile 0 into buf 0 (loads stay in flight into the loop)
  {
    char* L = smem;
    for (int i = w; i < 9; i += 4) gld16(xa_t + i * 512 + lane * 8, L + i * 1024);
    for (int i = w; i < 8; i += 4) gld16(b2_t + i * 512 + lane * 8, L + 9216 + i * 1024);
  }
  int cur = 0;
  for (int tile = 0; tile < 16; ++tile) {
    // issue next-tile loads into buf^1 (4-5 per wave), then counted wait:
    // own current-tile loads complete while next-tile loads remain in flight.
    if (tile + 1 < 16) {
      char* L = smem + (cur ^ 1) * 17408;
      const u16* ga = xa_t + (size_t)(tile + 1) * 4608;
      const u16* gb = b2_t + (size_t)(tile + 1) * 4096;
      for (int i = w; i < 9; i += 4) gld16(ga + i * 512 + lane * 8, L + i * 1024);
      for (int i = w; i < 8; i += 4) gld16(gb + i * 512 + lane * 8, L + 9216 + i * 1024);
      asm volatile("s_waitcnt vmcnt(4)" ::: "memory");
    } else {
      asm volatile("s_waitcnt vmcnt(0)" ::: "memory");
    }
    __builtin_amdgcn_s_barrier();        // all waves' current-tile data staged
    __builtin_amdgcn_sched_barrier(0);
    char* LA = smem + cur * 17408;
    char* LB = LA + 9216;
    // two independent d2 accumulator chains (k9 even -> a, odd -> b)
    __builtin_amdgcn_s_setprio(1);
    f32x16 d2a, d2b;
    {
      bf16x8 a0 = *(const bf16x8*)(LA + lane * 16);
      bf16x8 a1 = *(const bf16x8*)(LA + 1024 + lane * 16);
      d2a = __builtin_amdgcn_mfma_f32_32x32x16_bf16(a0, B1[0], zero, 0, 0, 0);
      d2b = __builtin_amdgcn_mfma_f32_32x32x16_bf16(a1, B1[1], zero, 0, 0, 0);
    }
#pragma unroll
    for (int k9 = 2; k9 < 9; ++k9) {
      bf16x8 av = *(const bf16x8*)(LA + k9 * 1024 + lane * 16);
      if (k9 & 1)
        d2b = __builtin_amdgcn_mfma_f32_32x32x16_bf16(av, B1[k9], d2b, 0, 0, 0);
      else
        d2a = __builtin_amdgcn_mfma_f32_32x32x16_bf16(av, B1[k9], d2a, 0, 0, 0);
    }
    __builtin_amdgcn_s_setprio(0);
    float p[16];
#pragma unroll
    for (int q = 0; q < 16; ++q) {
      p[q] = ((d2a[q] + d2b[q]) < 256.f) ? 1.f : 0.f;
      if (MODE == 0) dg += p[q];
    }
    u32 c[8];
#pragma unroll
    for (int pr = 0; pr < 8; ++pr)
      asm("v_cvt_pk_bf16_f32 %0, %1, %2" : "=v"(c[pr]) : "v"(p[2 * pr]), "v"(p[2 * pr + 1]));
    asm volatile("v_permlane32_swap_b32 %0, %1" : "+v"(c[0]), "+v"(c[2]));
    asm volatile("v_permlane32_swap_b32 %0, %1" : "+v"(c[1]), "+v"(c[3]));
    asm volatile("v_permlane32_swap_b32 %0, %1" : "+v"(c[4]), "+v"(c[6]));
    asm volatile("v_permlane32_swap_b32 %0, %1" : "+v"(c[5]), "+v"(c[7]));
    uint4 u0 = make_uint4(c[0], c[1], c[2], c[3]);
    uint4 u1 = make_uint4(c[4], c[5], c[6], c[7]);
    bf16x8 A2h0 = __builtin_bit_cast(bf16x8, u0);
    bf16x8 A2h1 = __builtin_bit_cast(bf16x8, u1);
    __builtin_amdgcn_s_setprio(1);
#pragma unroll
    for (int dt = 0; dt < 4; ++dt) {
      bf16x8 b20 = *(const bf16x8*)(LB + dt * 2048 + hi * 512 + r * 16);
      bf16x8 b21 = *(const bf16x8*)(LB + dt * 2048 + 1024 + hi * 512 + r * 16);
      acc2[dt] = __builtin_amdgcn_mfma_f32_32x32x16_bf16(A2h0, b20, acc2[dt], 0, 0, 0);
      acc2[dt] = __builtin_amdgcn_mfma_f32_32x32x16_bf16(A2h1, b21, acc2[dt], 0, 0, 0);
    }
    __builtin_amdgcn_s_setprio(0);
    // my LDS reads of buf cur are complete; then block-wide release so the
    // next iteration may overwrite it. Raw barrier: vmcnt NOT drained.
    asm volatile("s_waitcnt lgkmcnt(0)" ::: "memory");
    __builtin_amdgcn_sched_barrier(0);
    __builtin_amdgcn_s_barrier();
    cur ^= 1;
  }
  if (MODE == 0) {
    float dtot = dg + __shfl_xor(dg, 32);
    if (hi == 0) atomicAdd(&deg[b * NN + e0 + w * 32 + r], dtot);
    // direct fragment-layout store: Pbuf[ks][b][vt'=et*4+w][dt][h][hi2][r][8]
    u16* base = outP + ((size_t)(ks * NB + b) * 128 + (et * 4 + w)) * 4096;
#pragma unroll
    for (int dt = 0; dt < 4; ++dt)
#pragma unroll
      for (int h = 0; h < 2; ++h)
#pragma unroll
        for (int hi2 = 0; hi2 < 2; ++hi2) {
          int q0 = h * 8 + hi2 * 4;
          u32 w0 = pk2(acc2[dt][q0], acc2[dt][q0 + 1]);
          u32 w1 = pk2(acc2[dt][q0 + 2], acc2[dt][q0 + 3]);
          *(uint2*)(base + (((dt * 2 + h) * 2 + hi2) * 32 + r) * 8 + hi * 4) =
              make_uint2(w0, w1);
        }
  } else {
    // transpose to [row][d] rows for k_vfin
    u16* lsE = (u16*)smem + w * 4096;
#pragma unroll
    for (int dt = 0; dt < 4; ++dt)
#pragma unroll
      for (int q = 0; q < 16; ++q) {
        int e_l = (q & 3) + 8 * (q >> 2) + 4 * hi;
        lsE[e_l * 128 + dt * 32 + r] = f2bf(acc2[dt][q]);
      }
    __syncthreads();
    uint4* g4 = (uint4*)(outP + ((size_t)(ks * NB + b) * NN + e0) * 128);
    const uint4* l4 = (const uint4*)smem;
#pragma unroll
    for (int i = 0; i < 8; ++i) g4[t + i * 256] = l4[t + i * 256];
  }
}

// ---------------- k_escale: sum ks partials, scale 1/deg -> ED2 --------------
__global__ __launch_bounds__(256) void k_escale(const u16* __restrict__ PA,
                                                const float* __restrict__ deg,
                                                u16* __restrict__ ED2) {
  int m = blockIdx.x * 256 + threadIdx.x;      // 131072 threads, 2 items each
#pragma unroll
  for (int it = 0; it < 2; ++it, m += 131072) {
    int g = m & 511, vt = (m >> 9) & 127, b = m >> 16;
    int hi2 = (g >> 5) & 1, h = (g >> 6) & 1;
    int e0 = vt * 32 + h * 16 + hi2 * 8;
    float4 dg0 = *(const float4*)(deg + b * NN + e0);
    float4 dg1 = *(const float4*)(deg + b * NN + e0 + 4);
    float s[8];
#pragma unroll
    for (int j = 0; j < 8; ++j) s[j] = 0.f;
    size_t off = ((size_t)(b * 128 + vt) * 512 + g) * 8;
#pragma unroll
    for (int ksv = 0; ksv < KS; ++ksv) {
      uint4 pkv = *(const uint4*)(PA + (size_t)ksv * 2097152 + off);
      u32 wv[4] = {pkv.x, pkv.y, pkv.z, pkv.w};
#pragma unroll
      for (int p = 0; p < 4; ++p) {
        s[2 * p]     += bf2f((u16)(wv[p] & 0xFFFF));
        s[2 * p + 1] += bf2f((u16)(wv[p] >> 16));
      }
    }
    float iv[8];
    iv[0] = dg0.x; iv[1] = dg0.y; iv[2] = dg0.z; iv[3] = dg0.w;
    iv[4] = dg1.x; iv[5] = dg1.y; iv[6] = dg1.z; iv[7] = dg1.w;
    u32 o[4];
#pragma unroll
    for (int p = 0; p < 4; ++p) {
      float f0 = iv[2 * p]     > 0.f ? s[2 * p]     / iv[2 * p]     : 0.f;
      float f1 = iv[2 * p + 1] > 0.f ? s[2 * p + 1] / iv[2 * p + 1] : 0.f;
      o[p] = pk2(f0, f1);
    }
    *(uint4*)(ED2 + off) = make_uint4(o[0], o[1], o[2], o[3]);
  }
}

// ---------------- vert partials -> out[b][d][n] + residual + BN stats --------
__global__ __launch_bounds__(256) void k_vfin(const u16* __restrict__ P,
                                              const float* __restrict__ deg,
                                              const float* __restrict__ x,
                                              float* __restrict__ outp,
                                              float* __restrict__ bnsum,
                                              float* __restrict__ bnsq) {
  __shared__ float lsT[128][72];
  int blk = blockIdx.x;  int b = blk >> 6;  int n0 = (blk & 63) * 64;
  int t = threadIdx.x;
  {
    int n = t >> 2, q = t & 3;
    int i = n0 + n;
    float dv = deg[b * NN + i];
    float f = dv > 0.f ? 1.0f / dv : 0.f;
    size_t base = ((size_t)b * NN + i) * 128 + q * 32;
    float vs[32];
#pragma unroll
    for (int j = 0; j < 32; ++j) vs[j] = 0.f;
    for (int kss = 0; kss < KS; ++kss) {
      const u16* src = P + (size_t)kss * 2097152 + base;
#pragma unroll
      for (int ch = 0; ch < 4; ++ch) {
        uint4 pkv = *(const uint4*)(src + ch * 8);
        u32 wv[4] = {pkv.x, pkv.y, pkv.z, pkv.w};
#pragma unroll
        for (int pp = 0; pp < 4; ++pp) {
          vs[ch * 8 + 2 * pp]     += bf2f((u16)(wv[pp] & 0xFFFF));
          vs[ch * 8 + 2 * pp + 1] += bf2f((u16)(wv[pp] >> 16));
        }
      }
    }
#pragma unroll
    for (int j = 0; j < 32; ++j) lsT[q * 32 + j][n] = vs[j] * f;
  }
  __syncthreads();
  {
    int d = t >> 1, half = t & 1;
    const float* xr = x + ((size_t)b * CH + d) * NN + n0 + half * 32;
    float* orow = outp + ((size_t)b * CH + d) * NN + n0 + half * 32;
    float s = 0.f, s2 = 0.f;
#pragma unroll
    for (int i = 0; i < 32; ++i) {
      float v = lsT[d][half * 32 + i] + xr[i];
      orow[i] = v;
      s += v;  s2 += v * v;
    }
    s += __shfl_xor(s, 1);
    s2 += __shfl_xor(s2, 1);
    if (half == 0) { atomicAdd(&bnsum[d], s); atomicAdd(&bnsq[d], s2); }
  }
}

// ---------------- in-place BatchNorm(training) + SiLU ------------------------
__global__ void k_bn(float* __restrict__ y, const float* __restrict__ bnsum,
                     const float* __restrict__ bnsq, const float* __restrict__ gamma,
                     const float* __restrict__ beta) {
  int idx = blockIdx.x * 256 + threadIdx.x;   // 2M
  int d = (idx >> 12) & 127;
  const float cnt = (float)(NB * NN);
  float m = bnsum[d] / cnt;
  float var = bnsq[d] / cnt - m * m;
  float rs = rsqrtf(var + 1e-5f);
  float v = y[idx];
  float tt = (v - m) * rs * gamma[d] + beta[d];
  y[idx] = tt / (1.0f + expf(-tt));
}

extern "C" void kernel_launch(void* const* d_in, const int* in_sizes, int n_in,
                              void* d_out, int out_size, void* d_ws, size_t ws_size,
                              hipStream_t stream) {
  (void)in_sizes; (void)n_in; (void)out_size; (void)ws_size;
  const float* x     = (const float*)d_in[0];
  const float* W     = (const float*)d_in[1];
  const float* bfc   = (const float*)d_in[2];
  const float* gamma = (const float*)d_in[3];
  const float* beta  = (const float*)d_in[4];
  char* ws = (char*)d_ws;
  u16* Pbuf  = (u16*)ws;                       // 32 MB [ks8][b4][...]
  u16* XA    = (u16*)(ws + 33554432);          // 4.5 MB
  u16* XG    = (u16*)(ws + 38273024);          // 4.5 MB
  u16* XE2   = (u16*)(ws + 42991616);          // 4 MB
  u16* ED2   = (u16*)(ws + 47185920);          // 4 MB
  float* deg = (float*)(ws + 51380224);        // 64 KB
  float* bnsum = (float*)(ws + 51445760);      // 512 B
  float* bnsq  = (float*)(ws + 51446272);      // 512 B

  hipMemsetAsync(ws + 51380224, 0, 66560, stream);   // deg + bnsum + bnsq
  k_prep<<<NB * 64, 256, 0, stream>>>(x, XA, XG);
  k_xe<<<NB * 32, 256, 0, stream>>>(XA, W, bfc, XE2);
  // pass A: edge partials (fragment layout) + deg
  k_hyp<0><<<NB * 32 * KS, 256, 0, stream>>>(XA, XG, XE2, Pbuf, deg);
  k_escale<<<512, 256, 0, stream>>>(Pbuf, deg, ED2);
  // pass B: vert partials (row layout)
  k_hyp<1><<<NB * 32 * KS, 256, 0, stream>>>(XA, XG, ED2, Pbuf, deg);
  k_vfin<<<NB * 64, 256, 0, stream>>>(Pbuf, deg, x, (float*)d_out, bnsum, bnsq);
  k_bn<<<2097152 / 256, 256, 0, stream>>>((float*)d_out, bnsum, bnsq, gamma, beta);
}

// Round 8
// 175.892 us; speedup vs baseline: 1.0929x; 1.0929x over previous
//
#include <hip/hip_runtime.h>
#include <hip/hip_bf16.h>

#define NB 4
#define CH 128
#define NN 4096
#define KS 4                     // split of the K(v) dim in k_hyp

typedef short bf16x8 __attribute__((ext_vector_type(8)));
typedef float f32x4 __attribute__((ext_vector_type(4)));
typedef float f32x16 __attribute__((ext_vector_type(16)));
using u16 = unsigned short;
using u32 = unsigned int;

__device__ __forceinline__ u16 f2bf(float v) {
  return __builtin_bit_cast(u16, __float2bfloat16(v));
}
__device__ __forceinline__ float bf2f(u16 u) {
  return __builtin_bit_cast(float, ((u32)u) << 16);
}
__device__ __forceinline__ u32 pk2(float a, float b) {
  return (u32)f2bf(a) | ((u32)f2bf(b) << 16);
}

__device__ __forceinline__ void gld16(const void* g, void* l) {
  __builtin_amdgcn_global_load_lds((const __attribute__((address_space(1))) void*)g,
                                   (__attribute__((address_space(3))) void*)l,
                                   16, 0, 0);
}

// ---------------- k_prep: x[b][c][n] -> XA/XG fragment-order aug arrays ------
// Also zeroes deg/bnsum/bnsq (16640 floats) - replaces hipMemsetAsync.
__global__ __launch_bounds__(256) void k_prep(const float* __restrict__ x,
                                              u16* __restrict__ XA,
                                              u16* __restrict__ XG,
                                              float* __restrict__ zbuf) {
  __shared__ float ls[128][65];
  __shared__ float sqs[64];
  int blk = blockIdx.x;            // NB*64 = 256
  int b = blk >> 6;
  int n0 = (blk & 63) * 64;
  int t = threadIdx.x;
  if (t < 65) zbuf[blk * 65 + t] = 0.f;    // 256*65 = 16640 floats zeroed
  const float* xb = x + (size_t)b * CH * NN;
  {
    int j = t & 63, cb = t >> 6;
#pragma unroll
    for (int i = 0; i < 32; ++i) {
      int c = cb * 32 + i;
      ls[c][j] = xb[(size_t)c * NN + n0 + j];
    }
  }
  __syncthreads();
  if (t < 64) {
    float s = 0.f;
#pragma unroll
    for (int c = 0; c < 128; ++c) { float v = ls[c][t]; s += v * v; }
    sqs[t] = s;
  }
  __syncthreads();
  int v = t & 31, g = t >> 5;      // g = 0..7
  const u32 one2 = 0x3F803F80u;
#pragma unroll
  for (int vt2 = 0; vt2 < 2; ++vt2) {
    int j = vt2 * 32 + v;
    float sv = sqs[j];
    u16 shi = f2bf(sv);
    u16 slo = f2bf(sv - bf2f(shi));
    size_t tb = ((size_t)b * 128 + (n0 >> 5) + vt2) * 4608;
    for (int s = g; s < 18; s += 8) {
      int k9 = s >> 1, h = s & 1;
      int c0 = k9 * 16 + h * 8;
      u32 wa[4], wg[4];
      if (k9 < 8) {
#pragma unroll
        for (int p = 0; p < 4; ++p) {
          float va = ls[c0 + 2 * p][j], vb = ls[c0 + 2 * p + 1][j];
          wa[p] = pk2(va, vb);
          wg[p] = pk2(-2.f * va, -2.f * vb);
        }
      } else if (h == 0) {
        wa[0] = (u32)shi | ((u32)slo << 16); wa[1] = one2; wa[2] = 0u; wa[3] = 0u;
        wg[0] = one2; wg[1] = (u32)shi | ((u32)slo << 16); wg[2] = 0u; wg[3] = 0u;
      } else {
        wa[0] = wa[1] = wa[2] = wa[3] = 0u;
        wg[0] = wg[1] = wg[2] = wg[3] = 0u;
      }
      *(uint4*)(XA + tb + (size_t)s * 256 + v * 8) = make_uint4(wa[0], wa[1], wa[2], wa[3]);
      *(uint4*)(XG + tb + (size_t)s * 256 + v * 8) = make_uint4(wg[0], wg[1], wg[2], wg[3]);
    }
  }
}

// ---------------- k_xe: MFMA GEMM  xe = xf*W^T + b -> XE2 fragment layout ----
__global__ __launch_bounds__(256) void k_xe(const u16* __restrict__ XA,
                                            const float* __restrict__ W,
                                            const float* __restrict__ bfc,
                                            u16* __restrict__ XE2) {
  __shared__ __align__(16) char sw[32768];   // W bf16 [d][c], XOR-swizzled rows
  int t = threadIdx.x;
  int lane = t & 63, w = t >> 6;
  int r = lane & 31, hi = lane >> 5;
  int b = blockIdx.x >> 5, nt = blockIdx.x & 31;
  int vt = nt * 4 + w;
  {
    int d = t >> 1, half = t & 1;
    const float4* src = (const float4*)(W + (size_t)d * 128 + half * 64);
    int rowoff = d * 256, sz = (d & 7) << 4;
#pragma unroll
    for (int ch = 0; ch < 8; ++ch) {
      float4 f0 = src[ch * 2], f1 = src[ch * 2 + 1];
      *(uint4*)(sw + ((rowoff + half * 128 + ch * 16) ^ sz)) =
          make_uint4(pk2(f0.x, f0.y), pk2(f0.z, f0.w), pk2(f1.x, f1.y), pk2(f1.z, f1.w));
    }
  }
  float bias[4];
#pragma unroll
  for (int dt = 0; dt < 4; ++dt) bias[dt] = bfc[dt * 32 + r];
  __syncthreads();
  const u16* abase = XA + ((size_t)(b * 128 + vt)) * 4608;
  bf16x8 a[8];
#pragma unroll
  for (int k9 = 0; k9 < 8; ++k9)
    a[k9] = *(const bf16x8*)(abase + (k9 * 2 + hi) * 256 + r * 8);
  f32x16 acc[4];
#pragma unroll
  for (int dt = 0; dt < 4; ++dt)
#pragma unroll
    for (int q = 0; q < 16; ++q) acc[dt][q] = bias[dt];
#pragma unroll
  for (int k9 = 0; k9 < 8; ++k9) {
#pragma unroll
    for (int dt = 0; dt < 4; ++dt) {
      int d = dt * 32 + r;
      bf16x8 bf_ = *(const bf16x8*)(sw + ((d * 256 + k9 * 32 + hi * 16) ^ ((d & 7) << 4)));
      acc[dt] = __builtin_amdgcn_mfma_f32_32x32x16_bf16(a[k9], bf_, acc[dt], 0, 0, 0);
    }
  }
  u16* base = XE2 + ((size_t)(b * 128 + vt)) * 4096;
#pragma unroll
  for (int dt = 0; dt < 4; ++dt)
#pragma unroll
    for (int h = 0; h < 2; ++h)
#pragma unroll
      for (int hi2 = 0; hi2 < 2; ++hi2) {
        int q0 = h * 8 + hi2 * 4;
        u32 w0 = pk2(acc[dt][q0], acc[dt][q0 + 1]);
        u32 w1 = pk2(acc[dt][q0 + 2], acc[dt][q0 + 3]);
        *(uint2*)(base + (((dt * 2 + h) * 2 + hi2) * 32 + r) * 8 + hi * 4) =
            make_uint2(w0, w1);
      }
}

// ---------------- fused: P=(d2<256); out += P*B2 ; deg += rowsum(P) ----------
// MODE 0 (pass A): fragment-layout partials + deg atomics.
// MODE 1 (pass B): [row][d] layout partials, no deg.
// grid: 512 = b(4) x et(32) x ks(4); 4 waves, wave = 32 out-rows x 128 d.
// 2-tile software pipeline over 4-deep LDS buffers; single barrier per tile;
// stage-after-barrier (race-free: target buffer's readers all past barrier);
// counted vmcnt(3) keeps newest stage in flight across the barrier.
#define STAGE(tile, Lbase) do {                                              \
    const u16* ga_ = xa_t + (size_t)(tile) * 4608;                           \
    const u16* gb_ = b2_t + (size_t)(tile) * 4096;                           \
    char* L_ = (Lbase);                                                      \
    for (int i_ = w; i_ < 9; i_ += 4) gld16(ga_ + i_ * 512 + lane * 8, L_ + i_ * 1024); \
    for (int i_ = w; i_ < 8; i_ += 4) gld16(gb_ + i_ * 512 + lane * 8, L_ + 9216 + i_ * 1024); \
  } while (0)

#define D2CHAIN(dst, Lbase) do {                                             \
    const char* LA_ = (Lbase);                                               \
    __builtin_amdgcn_s_setprio(1);                                           \
    dst = __builtin_amdgcn_mfma_f32_32x32x16_bf16(                           \
        *(const bf16x8*)(LA_ + lane * 16), B1[0], zero, 0, 0, 0);            \
    _Pragma("unroll")                                                        \
    for (int k9_ = 1; k9_ < 9; ++k9_)                                        \
      dst = __builtin_amdgcn_mfma_f32_32x32x16_bf16(                         \
          *(const bf16x8*)(LA_ + k9_ * 1024 + lane * 16), B1[k9_], dst, 0, 0, 0); \
    __builtin_amdgcn_s_setprio(0);                                           \
  } while (0)

#define PACKPV(dd, Lbase) do {                                               \
    const char* LB_ = (Lbase) + 9216;                                        \
    float p_[16];                                                            \
    _Pragma("unroll")                                                        \
    for (int q_ = 0; q_ < 16; ++q_) {                                        \
      p_[q_] = (dd[q_] < 256.f) ? 1.f : 0.f;                                 \
      if (MODE == 0) dg += p_[q_];                                           \
    }                                                                        \
    u32 c_[8];                                                               \
    _Pragma("unroll")                                                        \
    for (int pr_ = 0; pr_ < 8; ++pr_)                                        \
      asm("v_cvt_pk_bf16_f32 %0, %1, %2" : "=v"(c_[pr_]) : "v"(p_[2*pr_]), "v"(p_[2*pr_+1])); \
    asm volatile("v_permlane32_swap_b32 %0, %1" : "+v"(c_[0]), "+v"(c_[2])); \
    asm volatile("v_permlane32_swap_b32 %0, %1" : "+v"(c_[1]), "+v"(c_[3])); \
    asm volatile("v_permlane32_swap_b32 %0, %1" : "+v"(c_[4]), "+v"(c_[6])); \
    asm volatile("v_permlane32_swap_b32 %0, %1" : "+v"(c_[5]), "+v"(c_[7])); \
    bf16x8 A2h0_ = __builtin_bit_cast(bf16x8, make_uint4(c_[0], c_[1], c_[2], c_[3])); \
    bf16x8 A2h1_ = __builtin_bit_cast(bf16x8, make_uint4(c_[4], c_[5], c_[6], c_[7])); \
    __builtin_amdgcn_s_setprio(1);                                           \
    _Pragma("unroll")                                                        \
    for (int dt_ = 0; dt_ < 4; ++dt_) {                                      \
      bf16x8 b20_ = *(const bf16x8*)(LB_ + dt_ * 2048 + hi * 512 + r * 16);  \
      bf16x8 b21_ = *(const bf16x8*)(LB_ + dt_ * 2048 + 1024 + hi * 512 + r * 16); \
      acc2[dt_] = __builtin_amdgcn_mfma_f32_32x32x16_bf16(A2h0_, b20_, acc2[dt_], 0, 0, 0); \
      acc2[dt_] = __builtin_amdgcn_mfma_f32_32x32x16_bf16(A2h1_, b21_, acc2[dt_], 0, 0, 0); \
    }                                                                        \
    __builtin_amdgcn_s_setprio(0);                                           \
  } while (0)

template <int MODE>
__global__ __launch_bounds__(256, 2) void k_hyp(const u16* __restrict__ XAg,
                                                const u16* __restrict__ XGg,
                                                const u16* __restrict__ B2g,
                                                u16* __restrict__ outP,
                                                float* __restrict__ deg) {
  __shared__ __align__(16) char smem[69632];   // 4 x 17408
  int t = threadIdx.x;
  int lane = t & 63, w = t >> 6;
  int r = lane & 31, hi = lane >> 5;
  int bid = blockIdx.x;
  int b = bid >> 7;
  int et = (bid >> 2) & 31;
  int ks = bid & 3;
  int e0 = et * 128;
  int vt0 = ks * 32;               // 32 v-tiles of 32 per split

  bf16x8 B1[9];
  {
    const u16* g = XGg + ((size_t)(b * 128 + et * 4 + w)) * 4608 + (hi * 32 + r) * 8;
#pragma unroll
    for (int k9 = 0; k9 < 9; ++k9) B1[k9] = *(const bf16x8*)(g + k9 * 512);
  }

  f32x16 acc2[4];
#pragma unroll
  for (int dt = 0; dt < 4; ++dt)
#pragma unroll
    for (int q = 0; q < 16; ++q) acc2[dt][q] = 0.f;
  float dg = 0.f;
  f32x16 zero;
#pragma unroll
  for (int q = 0; q < 16; ++q) zero[q] = 0.f;

  const u16* xa_t = XAg + ((size_t)(b * 128 + vt0)) * 4608;
  const u16* b2_t = B2g + ((size_t)(b * 128 + vt0)) * 4096;

  f32x16 d2X, d2Y;
  // prologue: stage tiles 0,1,2; prime d2(0)
  STAGE(0, smem);
  STAGE(1, smem + 17408);
  STAGE(2, smem + 2 * 17408);
  asm volatile("s_waitcnt vmcnt(3)" ::: "memory");   // tiles 0,1 complete
  __builtin_amdgcn_s_barrier();
  __builtin_amdgcn_sched_barrier(0);
  D2CHAIN(d2X, smem);                                // d2(0)

  for (int tt = 0; tt < 30; tt += 2) {
    // --- tile tt: pack/PV(tt) with d2X; compute d2(tt+1) into d2Y ---
    asm volatile("s_waitcnt vmcnt(3)" ::: "memory"); // tile tt+1 complete
    __builtin_amdgcn_s_barrier();
    __builtin_amdgcn_sched_barrier(0);
    STAGE(tt + 3, smem + ((tt + 3) & 3) * 17408);    // target's readers released
    D2CHAIN(d2Y, smem + ((tt + 1) & 3) * 17408);
    PACKPV(d2X, smem + (tt & 3) * 17408);
    asm volatile("s_waitcnt lgkmcnt(0)" ::: "memory");
    __builtin_amdgcn_sched_barrier(0);
    // --- tile tt+1: pack/PV(tt+1) with d2Y; compute d2(tt+2) into d2X ---
    asm volatile("s_waitcnt vmcnt(3)" ::: "memory"); // tile tt+2 complete
    __builtin_amdgcn_s_barrier();
    __builtin_amdgcn_sched_barrier(0);
    if (tt + 4 < 32) STAGE(tt + 4, smem + ((tt + 4) & 3) * 17408);
    D2CHAIN(d2X, smem + ((tt + 2) & 3) * 17408);
    PACKPV(d2Y, smem + ((tt + 1) & 3) * 17408);
    asm volatile("s_waitcnt lgkmcnt(0)" ::: "memory");
    __builtin_amdgcn_sched_barrier(0);
  }
  // tile 30: needs tile 31 fully staged for d2(31)
  asm volatile("s_waitcnt vmcnt(0)" ::: "memory");
  __builtin_amdgcn_s_barrier();
  __builtin_amdgcn_sched_barrier(0);
  D2CHAIN(d2Y, smem + (31 & 3) * 17408);
  PACKPV(d2X, smem + (30 & 3) * 17408);
  // tile 31 (no more staging; buffers stable)
  PACKPV(d2Y, smem + (31 & 3) * 17408);

  if (MODE == 0) {
    float dtot = dg + __shfl_xor(dg, 32);
    if (hi == 0) atomicAdd(&deg[b * NN + e0 + w * 32 + r], dtot);
    // direct fragment-layout store: Pbuf[ks][b][vt'=et*4+w][dt][h][hi2][r][8]
    u16* base = outP + ((size_t)(ks * NB + b) * 128 + (et * 4 + w)) * 4096;
#pragma unroll
    for (int dt = 0; dt < 4; ++dt)
#pragma unroll
      for (int h = 0; h < 2; ++h)
#pragma unroll
        for (int hi2 = 0; hi2 < 2; ++hi2) {
          int q0 = h * 8 + hi2 * 4;
          u32 w0 = pk2(acc2[dt][q0], acc2[dt][q0 + 1]);
          u32 w1 = pk2(acc2[dt][q0 + 2], acc2[dt][q0 + 3]);
          *(uint2*)(base + (((dt * 2 + h) * 2 + hi2) * 32 + r) * 8 + hi * 4) =
              make_uint2(w0, w1);
        }
  } else {
    // transpose to [row][d] rows for k_vfin (lsE regions disjoint from buf 3)
    __builtin_amdgcn_s_barrier();
    u16* lsE = (u16*)smem + w * 4096;
#pragma unroll
    for (int dt = 0; dt < 4; ++dt)
#pragma unroll
      for (int q = 0; q < 16; ++q) {
        int e_l = (q & 3) + 8 * (q >> 2) + 4 * hi;
        lsE[e_l * 128 + dt * 32 + r] = f2bf(acc2[dt][q]);
      }
    __syncthreads();
    uint4* g4 = (uint4*)(outP + ((size_t)(ks * NB + b) * NN + e0) * 128);
    const uint4* l4 = (const uint4*)smem;
#pragma unroll
    for (int i = 0; i < 8; ++i) g4[t + i * 256] = l4[t + i * 256];
  }
}

// ---------------- k_escale: sum ks partials, scale 1/deg -> ED2 --------------
__global__ __launch_bounds__(256) void k_escale(const u16* __restrict__ PA,
                                                const float* __restrict__ deg,
                                                u16* __restrict__ ED2) {
  int m = blockIdx.x * 256 + threadIdx.x;      // 131072 threads, 2 items each
#pragma unroll
  for (int it = 0; it < 2; ++it, m += 131072) {
    int g = m & 511, vt = (m >> 9) & 127, b = m >> 16;
    int hi2 = (g >> 5) & 1, h = (g >> 6) & 1;
    int e0 = vt * 32 + h * 16 + hi2 * 8;
    float4 dg0 = *(const float4*)(deg + b * NN + e0);
    float4 dg1 = *(const float4*)(deg + b * NN + e0 + 4);
    float s[8];
#pragma unroll
    for (int j = 0; j < 8; ++j) s[j] = 0.f;
    size_t off = ((size_t)(b * 128 + vt) * 512 + g) * 8;
#pragma unroll
    for (int ksv = 0; ksv < KS; ++ksv) {
      uint4 pkv = *(const uint4*)(PA + (size_t)ksv * 2097152 + off);
      u32 wv[4] = {pkv.x, pkv.y, pkv.z, pkv.w};
#pragma unroll
      for (int p = 0; p < 4; ++p) {
        s[2 * p]     += bf2f((u16)(wv[p] & 0xFFFF));
        s[2 * p + 1] += bf2f((u16)(wv[p] >> 16));
      }
    }
    float iv[8];
    iv[0] = dg0.x; iv[1] = dg0.y; iv[2] = dg0.z; iv[3] = dg0.w;
    iv[4] = dg1.x; iv[5] = dg1.y; iv[6] = dg1.z; iv[7] = dg1.w;
    u32 o[4];
#pragma unroll
    for (int p = 0; p < 4; ++p) {
      float f0 = iv[2 * p]     > 0.f ? s[2 * p]     / iv[2 * p]     : 0.f;
      float f1 = iv[2 * p + 1] > 0.f ? s[2 * p + 1] / iv[2 * p + 1] : 0.f;
      o[p] = pk2(f0, f1);
    }
    *(uint4*)(ED2 + off) = make_uint4(o[0], o[1], o[2], o[3]);
  }
}

// ---------------- vert partials -> out[b][d][n] + residual + BN stats --------
__global__ __launch_bounds__(256) void k_vfin(const u16* __restrict__ P,
                                              const float* __restrict__ deg,
                                              const float* __restrict__ x,
                                              float* __restrict__ outp,
                                              float* __restrict__ bnsum,
                                              float* __restrict__ bnsq) {
  __shared__ float lsT[128][72];
  int blk = blockIdx.x;  int b = blk >> 6;  int n0 = (blk & 63) * 64;
  int t = threadIdx.x;
  {
    int n = t >> 2, q = t & 3;
    int i = n0 + n;
    float dv = deg[b * NN + i];
    float f = dv > 0.f ? 1.0f / dv : 0.f;
    size_t base = ((size_t)b * NN + i) * 128 + q * 32;
    float vs[32];
#pragma unroll
    for (int j = 0; j < 32; ++j) vs[j] = 0.f;
    for (int kss = 0; kss < KS; ++kss) {
      const u16* src = P + (size_t)kss * 2097152 + base;
#pragma unroll
      for (int ch = 0; ch < 4; ++ch) {
        uint4 pkv = *(const uint4*)(src + ch * 8);
        u32 wv[4] = {pkv.x, pkv.y, pkv.z, pkv.w};
#pragma unroll
        for (int pp = 0; pp < 4; ++pp) {
          vs[ch * 8 + 2 * pp]     += bf2f((u16)(wv[pp] & 0xFFFF));
          vs[ch * 8 + 2 * pp + 1] += bf2f((u16)(wv[pp] >> 16));
        }
      }
    }
#pragma unroll
    for (int j = 0; j < 32; ++j) lsT[q * 32 + j][n] = vs[j] * f;
  }
  __syncthreads();
  {
    int d = t >> 1, half = t & 1;
    const float* xr = x + ((size_t)b * CH + d) * NN + n0 + half * 32;
    float* orow = outp + ((size_t)b * CH + d) * NN + n0 + half * 32;
    float s = 0.f, s2 = 0.f;
#pragma unroll
    for (int i = 0; i < 32; ++i) {
      float v = lsT[d][half * 32 + i] + xr[i];
      orow[i] = v;
      s += v;  s2 += v * v;
    }
    s += __shfl_xor(s, 1);
    s2 += __shfl_xor(s2, 1);
    if (half == 0) { atomicAdd(&bnsum[d], s); atomicAdd(&bnsq[d], s2); }
  }
}

// ---------------- in-place BatchNorm(training) + SiLU ------------------------
__global__ void k_bn(float* __restrict__ y, const float* __restrict__ bnsum,
                     const float* __restrict__ bnsq, const float* __restrict__ gamma,
                     const float* __restrict__ beta) {
  int idx = blockIdx.x * 256 + threadIdx.x;   // 2M
  int d = (idx >> 12) & 127;
  const float cnt = (float)(NB * NN);
  float m = bnsum[d] / cnt;
  float var = bnsq[d] / cnt - m * m;
  float rs = rsqrtf(var + 1e-5f);
  float v = y[idx];
  float tt = (v - m) * rs * gamma[d] + beta[d];
  y[idx] = tt / (1.0f + expf(-tt));
}

extern "C" void kernel_launch(void* const* d_in, const int* in_sizes, int n_in,
                              void* d_out, int out_size, void* d_ws, size_t ws_size,
                              hipStream_t stream) {
  (void)in_sizes; (void)n_in; (void)out_size; (void)ws_size;
  const float* x     = (const float*)d_in[0];
  const float* W     = (const float*)d_in[1];
  const float* bfc   = (const float*)d_in[2];
  const float* gamma = (const float*)d_in[3];
  const float* beta  = (const float*)d_in[4];
  char* ws = (char*)d_ws;
  u16* Pbuf  = (u16*)ws;                       // 16 MB [ks4][b4][...]
  u16* XA    = (u16*)(ws + 33554432);          // 4.5 MB
  u16* XG    = (u16*)(ws + 38273024);          // 4.5 MB
  u16* XE2   = (u16*)(ws + 42991616);          // 4 MB
  u16* ED2   = (u16*)(ws + 47185920);          // 4 MB
  float* deg = (float*)(ws + 51380224);        // 64 KB (+bnsum/bnsq contiguous)
  float* bnsum = (float*)(ws + 51445760);      // 512 B
  float* bnsq  = (float*)(ws + 51446272);      // 512 B

  k_prep<<<NB * 64, 256, 0, stream>>>(x, XA, XG, deg);  // also zeroes deg/bn*
  k_xe<<<NB * 32, 256, 0, stream>>>(XA, W, bfc, XE2);
  // pass A: edge partials (fragment layout) + deg
  k_hyp<0><<<NB * 32 * KS, 256, 0, stream>>>(XA, XG, XE2, Pbuf, deg);
  k_escale<<<512, 256, 0, stream>>>(Pbuf, deg, ED2);
  // pass B: vert partials (row layout)
  k_hyp<1><<<NB * 32 * KS, 256, 0, stream>>>(XA, XG, ED2, Pbuf, deg);
  k_vfin<<<NB * 64, 256, 0, stream>>>(Pbuf, deg, x, (float*)d_out, bnsum, bnsq);
  k_bn<<<2097152 / 256, 256, 0, stream>>>((float*)d_out, bnsum, bnsq, gamma, beta);
}